// Round 1
// baseline (219.677 us; speedup 1.0000x reference)
//
#include <hip/hip_runtime.h>

// out[b, i] = in[b, perm[i]]  for b in [0, BATCH), i in [0, N)
// N = 1024, BATCH = 131072, fp32. Pure memory-bound gather.

#define NCOLS 1024
#define THREADS 256   // 4 waves; each thread owns 4 consecutive output columns

__global__ __launch_bounds__(THREADS) void
gather_perm_kernel(const float* __restrict__ in,
                   const int* __restrict__ perm,
                   float* __restrict__ out,
                   int batch)
{
    __shared__ int sperm[NCOLS];
    // Stage perm (4 KB) into LDS once per block.
    for (int i = threadIdx.x; i < NCOLS; i += THREADS)
        sperm[i] = perm[i];
    __syncthreads();

    const int t = threadIdx.x;
    // Hoist this thread's 4 gather indices into registers for the row loop.
    const int p0 = sperm[4 * t + 0];
    const int p1 = sperm[4 * t + 1];
    const int p2 = sperm[4 * t + 2];
    const int p3 = sperm[4 * t + 3];

    for (int b = blockIdx.x; b < batch; b += gridDim.x) {
        const float* __restrict__ row = in + (size_t)b * NCOLS;
        float4 v;
        v.x = row[p0];
        v.y = row[p1];
        v.z = row[p2];
        v.w = row[p3];
        *reinterpret_cast<float4*>(out + (size_t)b * NCOLS + 4 * t) = v;
    }
}

extern "C" void kernel_launch(void* const* d_in, const int* in_sizes, int n_in,
                              void* d_out, int out_size, void* d_ws, size_t ws_size,
                              hipStream_t stream)
{
    const float* features = (const float*)d_in[0];
    const int*   perm     = (const int*)d_in[1];
    float*       out      = (float*)d_out;

    const int batch = out_size / NCOLS;   // 131072

    int grid = batch < 8192 ? batch : 8192;
    gather_perm_kernel<<<grid, THREADS, 0, stream>>>(features, perm, out, batch);
}

// Round 2
// 215.850 us; speedup vs baseline: 1.0177x; 1.0177x over previous
//
#include <hip/hip_runtime.h>

// out[b, i] = in[b, perm[i]]  for b in [0, 131072), i in [0, 1024), fp32.
// Strategy: coalesced float4 global read -> contiguous LDS write ->
// LDS-side gather (perm in registers) -> coalesced float4 global write.
// Double-buffered LDS: one barrier per row; next row's global load issued
// before the barrier so HBM latency hides under gather+store.

#define NCOLS 1024
#define THREADS 256   // 4 waves; each thread owns 4 consecutive columns

__global__ __launch_bounds__(THREADS) void
permute_rows_lds(const float* __restrict__ in,
                 const int* __restrict__ perm,
                 float* __restrict__ out,
                 int batch)
{
    __shared__ float buf[2][NCOLS];   // 8 KB double buffer

    const int t = threadIdx.x;

    // This thread's 4 gather indices (element offsets within a row),
    // hoisted to registers once.
    const int p0 = perm[4 * t + 0];
    const int p1 = perm[4 * t + 1];
    const int p2 = perm[4 * t + 2];
    const int p3 = perm[4 * t + 3];

    const int g = gridDim.x;
    int b = blockIdx.x;
    if (b >= batch) return;   // uniform per block

    // Prologue: load first row (coalesced 16 B/lane).
    float4 v = *reinterpret_cast<const float4*>(in + (size_t)b * NCOLS + 4 * t);

    int cur = 0;
    while (b < batch) {
        // Contiguous LDS write (conflict-free ds_write_b128).
        *reinterpret_cast<float4*>(&buf[cur][4 * t]) = v;

        // Issue next row's global load BEFORE the barrier so it overlaps
        // with the gather + store phase.
        const int bn = b + g;
        float4 vn;
        if (bn < batch)
            vn = *reinterpret_cast<const float4*>(in + (size_t)bn * NCOLS + 4 * t);

        __syncthreads();   // buf[cur] now fully populated

        // LDS-side gather; banks spread across the 1/3/5/7-stride runs.
        float4 w;
        w.x = buf[cur][p0];
        w.y = buf[cur][p1];
        w.z = buf[cur][p2];
        w.w = buf[cur][p3];

        // Coalesced 16 B/lane global write.
        *reinterpret_cast<float4*>(out + (size_t)b * NCOLS + 4 * t) = w;

        v = vn;
        b = bn;
        cur ^= 1;
        // No second barrier needed: writes to buf[cur^1] next iteration are
        // ordered against this iteration's reads by the barrier above
        // (double-buffer argument: a wave can only reach iteration k+2's
        // write after every wave passed iteration k+1's barrier, which is
        // after iteration k's reads).
    }
}

extern "C" void kernel_launch(void* const* d_in, const int* in_sizes, int n_in,
                              void* d_out, int out_size, void* d_ws, size_t ws_size,
                              hipStream_t stream)
{
    const float* features = (const float*)d_in[0];
    const int*   perm     = (const int*)d_in[1];
    float*       out      = (float*)d_out;

    const int batch = out_size / NCOLS;   // 131072

    int grid = batch < 8192 ? batch : 8192;
    permute_rows_lds<<<grid, THREADS, 0, stream>>>(features, perm, out, batch);
}

// Round 3
// 203.534 us; speedup vs baseline: 1.0793x; 1.0605x over previous
//
#include <hip/hip_runtime.h>

// out[b, i] = in[b, perm[i]]  for b in [0, 131072), i in [0, 1024), fp32.
//
// Wave-private staging, ZERO barriers:
//  - each wave owns buf[w][2][1024] (8 KB LDS), processes 2 rows/iteration
//  - global reads/writes: coalesced float4 (16 B/lane, 1 KB/wave-instr)
//  - write->gather ordering within a wave is program order + lgkmcnt
//    (no __syncthreads => no s_waitcnt vmcnt(0) drains; loads stay in flight)
//  - perm indices live in registers (16 per lane), loaded once as int4

#define NCOLS 1024
#define THREADS 256
#define WPB 4   // waves per block

__global__ __launch_bounds__(THREADS) void
permute_rows_wavepriv(const float* __restrict__ in,
                      const int* __restrict__ perm,
                      float* __restrict__ out,
                      int batch)
{
    __shared__ float buf[WPB][2][NCOLS];   // 32 KB per block
    const int w = threadIdx.x >> 6;
    const int l = threadIdx.x & 63;

    // 16 gather indices per lane: out col c = 256*k + 4*l + j, k,j in [0,4).
    int4 p[4];
#pragma unroll
    for (int k = 0; k < 4; ++k)
        p[k] = *reinterpret_cast<const int4*>(perm + 256 * k + 4 * l);

    const int gw = blockIdx.x * WPB + w;    // global wave id
    const int nw = gridDim.x * WPB;         // total waves

    for (int b = gw; b < batch; b += 2 * nw) {
        const int b2 = b + nw;
        const bool has2 = (b2 < batch);

        // ---- issue ALL global loads for both rows (8 KB/wave in flight) ----
        const float* __restrict__ r0 = in + (size_t)b * NCOLS;
        const float* __restrict__ r1 = in + (size_t)(has2 ? b2 : b) * NCOLS;
        float4 v0[4], v1[4];
#pragma unroll
        for (int k = 0; k < 4; ++k)
            v0[k] = *reinterpret_cast<const float4*>(r0 + 256 * k + 4 * l);
#pragma unroll
        for (int k = 0; k < 4; ++k)
            v1[k] = *reinterpret_cast<const float4*>(r1 + 256 * k + 4 * l);

        // ---- stage both rows into this wave's private LDS ----
        float* s0 = buf[w][0];
        float* s1 = buf[w][1];
#pragma unroll
        for (int k = 0; k < 4; ++k)
            *reinterpret_cast<float4*>(s0 + 256 * k + 4 * l) = v0[k];
#pragma unroll
        for (int k = 0; k < 4; ++k)
            *reinterpret_cast<float4*>(s1 + 256 * k + 4 * l) = v1[k];

        // ---- gather (wave-synchronous: lockstep + compiler lgkmcnt) ----
        float4 o0[4], o1[4];
#pragma unroll
        for (int k = 0; k < 4; ++k) {
            o0[k].x = s0[p[k].x];
            o0[k].y = s0[p[k].y];
            o0[k].z = s0[p[k].z];
            o0[k].w = s0[p[k].w];
        }
#pragma unroll
        for (int k = 0; k < 4; ++k) {
            o1[k].x = s1[p[k].x];
            o1[k].y = s1[p[k].y];
            o1[k].z = s1[p[k].z];
            o1[k].w = s1[p[k].w];
        }

        // ---- coalesced stores ----
        float* __restrict__ q0 = out + (size_t)b * NCOLS;
#pragma unroll
        for (int k = 0; k < 4; ++k)
            *reinterpret_cast<float4*>(q0 + 256 * k + 4 * l) = o0[k];
        if (has2) {
            float* __restrict__ q1 = out + (size_t)b2 * NCOLS;
#pragma unroll
            for (int k = 0; k < 4; ++k)
                *reinterpret_cast<float4*>(q1 + 256 * k + 4 * l) = o1[k];
        }
    }
}

extern "C" void kernel_launch(void* const* d_in, const int* in_sizes, int n_in,
                              void* d_out, int out_size, void* d_ws, size_t ws_size,
                              hipStream_t stream)
{
    const float* features = (const float*)d_in[0];
    const int*   perm     = (const int*)d_in[1];
    float*       out      = (float*)d_out;

    const int batch = out_size / NCOLS;   // 131072

    const int grid = 4096;   // 16384 waves; 8 rows per wave (2 per iteration)
    permute_rows_wavepriv<<<grid, THREADS, 0, stream>>>(features, perm, out, batch);
}